// Round 1
// baseline (17.261 us; speedup 1.0000x reference)
//
#include <hip/hip_runtime.h>

// Problem constants (b=256, c_cls=1, h=w=192)
#define B_   256
#define W_   192
#define HW_  36864          // 192*192
#define SCALE_ 191.0f       // h-1 == w-1
#define NTHREADS 512
#define VEC_PER_THREAD 18   // HW_/4 / NTHREADS = 9216/512

// Kernel 1: per-sample argmax over cls map + smooth-L1 terms -> ws[b]
__global__ __launch_bounds__(NTHREADS)
void locloss_argmax_kernel(const float* __restrict__ cls,
                           const float* __restrict__ loc,
                           const float* __restrict__ cr,
                           float* __restrict__ ws) {
    const int b = blockIdx.x;
    const int t = threadIdx.x;
    const float4* __restrict__ c4 = (const float4*)(cls + (size_t)b * HW_);

    float bv = -INFINITY;
    int   bi = 0x7FFFFFFF;

#pragma unroll
    for (int it = 0; it < VEC_PER_THREAD; ++it) {
        const int v = t + it * NTHREADS;      // float4 index
        const float4 x = c4[v];
        const int base = v * 4;
        if (x.x > bv || (x.x == bv && base     < bi)) { bv = x.x; bi = base;     }
        if (x.y > bv || (x.y == bv && base + 1 < bi)) { bv = x.y; bi = base + 1; }
        if (x.z > bv || (x.z == bv && base + 2 < bi)) { bv = x.z; bi = base + 2; }
        if (x.w > bv || (x.w == bv && base + 3 < bi)) { bv = x.w; bi = base + 3; }
    }

    // wave (64-lane) reduction: max value, smallest index on ties
#pragma unroll
    for (int off = 32; off >= 1; off >>= 1) {
        const float ov = __shfl_down(bv, off);
        const int   oi = __shfl_down(bi, off);
        if (ov > bv || (ov == bv && oi < bi)) { bv = ov; bi = oi; }
    }

    __shared__ float sv[NTHREADS / 64];
    __shared__ int   si[NTHREADS / 64];
    const int wid = t >> 6;
    if ((t & 63) == 0) { sv[wid] = bv; si[wid] = bi; }
    __syncthreads();

    if (t == 0) {
#pragma unroll
        for (int wv = 1; wv < NTHREADS / 64; ++wv) {
            if (sv[wv] > bv || (sv[wv] == bv && si[wv] < bi)) { bv = sv[wv]; bi = si[wv]; }
        }
        const int r = bi / W_;
        const int c = bi - r * W_;

        const size_t lbase = (size_t)b * 2 * HW_ + (size_t)r * W_ + c;
        const float l0 = loc[lbase];
        const float l1 = loc[lbase + HW_];

        const float bias0 = cr[2 * b]     * SCALE_ - (float)r;
        const float bias1 = cr[2 * b + 1] * SCALE_ - (float)c;

        const float d0 = fabsf(l0 - bias0);
        const float d1 = fabsf(l1 - bias1);
        const float s0 = (d0 < 1.0f) ? 0.5f * d0 * d0 : d0 - 0.5f;
        const float s1 = (d1 < 1.0f) ? 0.5f * d1 * d1 : d1 - 0.5f;
        ws[b] = s0 + s1;
    }
}

// Kernel 2: reduce 256 per-sample sums -> mean over 2*B elements
__global__ __launch_bounds__(256)
void locloss_finalize_kernel(const float* __restrict__ ws, float* __restrict__ out) {
    const int t = threadIdx.x;
    float v = ws[t];
#pragma unroll
    for (int off = 32; off >= 1; off >>= 1) v += __shfl_down(v, off);

    __shared__ float s[4];
    if ((t & 63) == 0) s[t >> 6] = v;
    __syncthreads();
    if (t == 0) out[0] = (s[0] + s[1] + s[2] + s[3]) * (1.0f / (2.0f * B_));
}

extern "C" void kernel_launch(void* const* d_in, const int* in_sizes, int n_in,
                              void* d_out, int out_size, void* d_ws, size_t ws_size,
                              hipStream_t stream) {
    const float* cls = (const float*)d_in[0];   // (256,1,192,192) f32
    const float* loc = (const float*)d_in[1];   // (256,2,192,192) f32
    const float* cr  = (const float*)d_in[2];   // (256,2) f32
    float* out = (float*)d_out;
    float* ws  = (float*)d_ws;                  // 256 floats used

    locloss_argmax_kernel<<<B_, NTHREADS, 0, stream>>>(cls, loc, cr, ws);
    locloss_finalize_kernel<<<1, 256, 0, stream>>>(ws, out);
}

// Round 2
// 16.390 us; speedup vs baseline: 1.0532x; 1.0532x over previous
//
#include <hip/hip_runtime.h>

// Problem constants (b=256, c_cls=1, h=w=192)
#define B_      256
#define W_      192
#define HW_     36864        // 192*192
#define SCALE_  191.0f       // h-1 == w-1
#define SPLIT_  9            // chunks per sample
#define NB1_    (B_ * SPLIT_)        // 2304 blocks in stage 1
#define NT1_    256
#define V4_PER_CHUNK 1024    // (HW_/4)/SPLIT_ = 9216/9
#define V4_PER_THREAD 4      // 1024/256

// Stage 1: per-(sample,chunk) partial argmax -> ws[block] = {max, idx}
__global__ __launch_bounds__(NT1_)
void locloss_partial_argmax(const float* __restrict__ cls,
                            float2* __restrict__ ws) {
    const int blk = blockIdx.x;
    const int b   = blk / SPLIT_;
    const int s   = blk - b * SPLIT_;
    const int t   = threadIdx.x;

    // float4 base offset for this chunk
    const float4* __restrict__ c4 =
        (const float4*)(cls) + (size_t)b * (HW_ / 4) + (size_t)s * V4_PER_CHUNK;
    const int elem_base = s * (V4_PER_CHUNK * 4);   // element index within sample

    float bv = -INFINITY;
    int   bi = 0x7FFFFFFF;

#pragma unroll
    for (int it = 0; it < V4_PER_THREAD; ++it) {
        const int v = t + it * NT1_;                // float4 index within chunk
        const float4 x = c4[v];
        const int base = elem_base + v * 4;
        if (x.x > bv || (x.x == bv && base     < bi)) { bv = x.x; bi = base;     }
        if (x.y > bv || (x.y == bv && base + 1 < bi)) { bv = x.y; bi = base + 1; }
        if (x.z > bv || (x.z == bv && base + 2 < bi)) { bv = x.z; bi = base + 2; }
        if (x.w > bv || (x.w == bv && base + 3 < bi)) { bv = x.w; bi = base + 3; }
    }

    // wave (64-lane) reduction: max value, smallest index on ties
#pragma unroll
    for (int off = 32; off >= 1; off >>= 1) {
        const float ov = __shfl_down(bv, off);
        const int   oi = __shfl_down(bi, off);
        if (ov > bv || (ov == bv && oi < bi)) { bv = ov; bi = oi; }
    }

    __shared__ float sv[NT1_ / 64];
    __shared__ int   si[NT1_ / 64];
    const int wid = t >> 6;
    if ((t & 63) == 0) { sv[wid] = bv; si[wid] = bi; }
    __syncthreads();

    if (t == 0) {
#pragma unroll
        for (int wv = 1; wv < NT1_ / 64; ++wv) {
            if (sv[wv] > bv || (sv[wv] == bv && si[wv] < bi)) { bv = sv[wv]; bi = si[wv]; }
        }
        ws[blk] = make_float2(bv, __int_as_float(bi));
    }
}

// Stage 2: combine SPLIT_ partials per sample, gather loc, smooth-L1, mean.
__global__ __launch_bounds__(B_)
void locloss_finalize(const float2* __restrict__ ws,
                      const float* __restrict__ loc,
                      const float* __restrict__ cr,
                      float* __restrict__ out) {
    const int b = threadIdx.x;    // one thread per sample

    float bv = -INFINITY;
    int   bi = 0x7FFFFFFF;
    // chunks iterated in ascending-index order; strict > keeps first occurrence
#pragma unroll
    for (int s = 0; s < SPLIT_; ++s) {
        const float2 p = ws[b * SPLIT_ + s];
        const float v = p.x;
        const int   i = __float_as_int(p.y);
        if (v > bv) { bv = v; bi = i; }
    }

    const int r = bi / W_;
    const int c = bi - r * W_;

    const size_t lbase = (size_t)b * 2 * HW_ + (size_t)r * W_ + c;
    const float l0 = loc[lbase];
    const float l1 = loc[lbase + HW_];

    const float bias0 = cr[2 * b]     * SCALE_ - (float)r;
    const float bias1 = cr[2 * b + 1] * SCALE_ - (float)c;

    const float d0 = fabsf(l0 - bias0);
    const float d1 = fabsf(l1 - bias1);
    const float s0 = (d0 < 1.0f) ? 0.5f * d0 * d0 : d0 - 0.5f;
    const float s1 = (d1 < 1.0f) ? 0.5f * d1 * d1 : d1 - 0.5f;
    float v = s0 + s1;

    // block reduction over 256 threads (4 waves)
#pragma unroll
    for (int off = 32; off >= 1; off >>= 1) v += __shfl_down(v, off);

    __shared__ float sh[4];
    if ((b & 63) == 0) sh[b >> 6] = v;
    __syncthreads();
    if (b == 0) out[0] = (sh[0] + sh[1] + sh[2] + sh[3]) * (1.0f / (2.0f * B_));
}

extern "C" void kernel_launch(void* const* d_in, const int* in_sizes, int n_in,
                              void* d_out, int out_size, void* d_ws, size_t ws_size,
                              hipStream_t stream) {
    const float* cls = (const float*)d_in[0];   // (256,1,192,192) f32
    const float* loc = (const float*)d_in[1];   // (256,2,192,192) f32
    const float* cr  = (const float*)d_in[2];   // (256,2) f32
    float* out = (float*)d_out;
    float2* ws = (float2*)d_ws;                 // NB1_ float2 = 18.4 KB used

    locloss_partial_argmax<<<NB1_, NT1_, 0, stream>>>(cls, ws);
    locloss_finalize<<<1, B_, 0, stream>>>(ws, loc, cr, out);
}